// Round 1
// baseline (225.342 us; speedup 1.0000x reference)
//
#include <hip/hip_runtime.h>

// ---------------------------------------------------------------------------
// HIDecoder: fused  y=z@Wy^T+by ; lin_{m,v}=einsum(gamma,W{m,v})+b ; gaussian
// log-lik epilogue.
//
// Key trick: gamma is not an output, so fold the einsum into the GEMM:
//   lin_m[b,t,d] = sum_k z[b,k] * Weff_m[t,d,k],
//   Weff_m[t,d,k] = sum_y Wm[t,d,y]*Wy[t*32+y,k]
//   beff_m[t,d]   = bm[t,d] + sum_y by[t*32+y]*Wm[t,d,y]
// => one (32768 x 512) x (512 x 256) GEMM in bf16 MFMA instead of a
//    (32768 x 2048 x 256) fp32 GEMM + einsums.
//
// Layout of the 512 fused columns: n = t*8 + j ; j in [0,4) -> lin_m[d=j],
// j in [4,8) -> lin_v[d=j-4]. So each t owns 8 consecutive columns.
// ---------------------------------------------------------------------------

#define Bsz   32768
#define Tsz   64
#define Dsz   4
#define Ysz   32
#define Zsz   256
#define Nsz   512            // T*D*2 fused columns
#define BTtot (Bsz * Tsz)    // 2097152
#define EPS_  1e-3f
#define LOG2PI_ 1.8378770664093453f

#define BM       16          // rows per block
#define ASTRIDE  264         // bf16 units per staged z row (264*2=528B, 16B-aligned rows)
#define TP       145         // fp32 words per t in lin_lds (odd vs 32 banks)

typedef __attribute__((ext_vector_type(4))) float  f32x4;
typedef __attribute__((ext_vector_type(8))) short  short8;
typedef __attribute__((ext_vector_type(2))) unsigned int uint2v;

static __device__ __forceinline__ unsigned short f2bf(float f) {
    unsigned int u = __float_as_uint(f);
    unsigned int r = u + 0x7fffu + ((u >> 16) & 1u);   // RNE
    return (unsigned short)(r >> 16);
}

// ---------------------------------------------------------------------------
// Prep: build Weff (512 x 256, bf16 bits in ushort) and beff (512, fp32).
// One block per fused column n; thread k = Z index.
// ---------------------------------------------------------------------------
__global__ void hidec_prep(const float* __restrict__ Wy, const float* __restrict__ by,
                           const float* __restrict__ Wm, const float* __restrict__ bm,
                           const float* __restrict__ Wv, const float* __restrict__ bv,
                           unsigned short* __restrict__ weff, float* __restrict__ beff) {
    int n = blockIdx.x;              // 0..511
    int t = n >> 3;
    int j = n & 7;
    int d = j & 3;
    const float* M  = ((j < 4) ? Wm : Wv) + (t * Dsz + d) * Ysz;   // 32 floats
    int k = threadIdx.x;             // 0..255
    const float* wyr = Wy + (size_t)(t * Ysz) * Zsz + k;
    float acc = 0.f;
#pragma unroll
    for (int y = 0; y < Ysz; ++y)
        acc += M[y] * wyr[(size_t)y * Zsz];
    weff[(size_t)n * Zsz + k] = f2bf(acc);
    if (k == 0) {
        float s = ((j < 4) ? bm : bv)[t * Dsz + d];
        for (int y = 0; y < Ysz; ++y)
            s += by[t * Ysz + y] * M[y];
        beff[n] = s;
    }
}

// ---------------------------------------------------------------------------
// Main fused kernel. Grid = B/BM = 2048 blocks x 256 threads (4 waves).
// Wave w owns columns [w*128, (w+1)*128) as 8 MFMA 16x16 tiles.
// z tile (16x256) staged to LDS as bf16 ONCE; W_eff read from global (L2).
// ---------------------------------------------------------------------------
__global__ __launch_bounds__(256, 3)
void hidec_main(const float* __restrict__ z, const float* __restrict__ bx,
                const int* __restrict__ miss, const float* __restrict__ dmean,
                const float* __restrict__ dvarp, const unsigned short* __restrict__ weff,
                const float* __restrict__ beff, float* __restrict__ out) {
    __shared__ unsigned short a_lds[BM * ASTRIDE];   // 8448 B
    __shared__ float lin_lds[Tsz * TP];              // 37120 B

    const int tid  = threadIdx.x;
    const int blk  = blockIdx.x;
    const long row0 = (long)blk * BM;

    // ---- stage z (16 rows x 256 fp32) -> bf16 LDS -------------------------
#pragma unroll
    for (int i = 0; i < 4; ++i) {
        int idx4 = tid + i * 256;        // 1024 float4-groups
        int r  = idx4 >> 6;              // row 0..15
        int c4 = idx4 & 63;              // float4 column
        float4 v = *(const float4*)(z + (row0 + r) * Zsz + c4 * 4);
        uint2v p;
        p.x = (unsigned int)f2bf(v.x) | ((unsigned int)f2bf(v.y) << 16);
        p.y = (unsigned int)f2bf(v.z) | ((unsigned int)f2bf(v.w) << 16);
        *(uint2v*)&a_lds[r * ASTRIDE + c4 * 4] = p;
    }
    __syncthreads();

    // ---- GEMM: 16 rows x 512 cols x K=256, bf16 MFMA 16x16x32 -------------
    const int lane = tid & 63;
    const int w    = tid >> 6;       // wave 0..3
    const int c    = lane & 15;      // col within tile / A row
    const int q    = lane >> 4;      // quad

    f32x4 acc[8];
#pragma unroll
    for (int i = 0; i < 8; ++i) acc[i] = (f32x4){0.f, 0.f, 0.f, 0.f};

#pragma unroll
    for (int kk = 0; kk < 8; ++kk) {
        // A fragment: A[m=c][k=kk*32 + q*8 + j]
        short8 a = *(const short8*)&a_lds[c * ASTRIDE + kk * 32 + q * 8];
#pragma unroll
        for (int nni = 0; nni < 8; ++nni) {
            int n = w * 128 + nni * 16 + c;   // B row (= fused column)
            short8 b = *(const short8*)(weff + (size_t)n * Zsz + kk * 32 + q * 8);
            acc[nni] = __builtin_amdgcn_mfma_f32_16x16x32_bf16(a, b, acc[nni], 0, 0, 0);
        }
    }

    // ---- epilogue: accs (+bias) -> swizzled LDS ---------------------------
    // C layout: col = lane&15, row = quad*4 + reg  (verified m89/m91)
#pragma unroll
    for (int nni = 0; nni < 8; ++nni) {
        int n = w * 128 + nni * 16 + c;
        float bb = beff[n];
        int t = n >> 3;
        int j = n & 7;
#pragma unroll
        for (int reg = 0; reg < 4; ++reg) {
            int r = q * 4 + reg;             // row 0..15
            lin_lds[t * TP + r * 9 + j] = acc[nni][reg] + bb;
        }
    }
    __syncthreads();

    // ---- postprocess: 16 rows x 64 t = 1024 tasks, 4 per thread -----------
#pragma unroll
    for (int pp = 0; pp < 4; ++pp) {
        int task = pp * 256 + tid;
        int t = task & 63;
        int r = task >> 6;
        long bt = (row0 + r) * Tsz + t;

        const float* lp = &lin_lds[t * TP + r * 9];   // [0..3]=lin_m, [4..7]=lin_v

        float4 x4  = *(const float4*)(bx + bt * 4);
        float4 dm4 = *(const float4*)(dmean + t * 4);
        float4 dv4 = *(const float4*)(dvarp + t * 4);
        float xa[4]  = {x4.x, x4.y, x4.z, x4.w};
        float dma[4] = {dm4.x, dm4.y, dm4.z, dm4.w};
        float dva[4] = {dv4.x, dv4.y, dv4.z, dv4.w};

        float mean_o[4], var_o[4];
        float s = 0.f;
#pragma unroll
        for (int d = 0; d < 4; ++d) {
            float dvar = fmaxf(dva[d], EPS_);
            float mean = sqrtf(dvar) * lp[d] + dma[d];
            float v    = lp[4 + d];
            // softplus, numerically safe
            float sp   = fmaxf(v, 0.f) + log1pf(__expf(-fabsf(v)));
            float ev   = fminf(fmaxf(sp, EPS_), 1e20f);
            float var  = dvar * ev;
            float diff = xa[d] - mean;
            s += diff * diff / var + __logf(var);
            mean_o[d] = mean;
            var_o[d]  = var;
        }
        float logp = -0.5f * (s + 4.f * LOG2PI_);
        float mk = (float)miss[bt];

        out[bt]          = logp * mk;          // log_p_x
        out[BTtot + bt]  = logp * (1.f - mk);  // log_p_x_missing

        float4 mo = {mean_o[0], mean_o[1], mean_o[2], mean_o[3]};
        float4 vo = {var_o[0], var_o[1], var_o[2], var_o[3]};
        *(float4*)(out + 2L * BTtot + bt * 4) = mo;   // mean_x
        *(float4*)(out + 6L * BTtot + bt * 4) = vo;   // var_x
    }
}

// ---------------------------------------------------------------------------
extern "C" void kernel_launch(void* const* d_in, const int* in_sizes, int n_in,
                              void* d_out, int out_size, void* d_ws, size_t ws_size,
                              hipStream_t stream) {
    const float* z     = (const float*)d_in[0];
    const float* bx    = (const float*)d_in[1];
    const int*   miss  = (const int*)d_in[2];
    const float* dmean = (const float*)d_in[3];
    const float* dvar  = (const float*)d_in[4];
    const float* Wy    = (const float*)d_in[5];
    const float* by    = (const float*)d_in[6];
    const float* Wm    = (const float*)d_in[7];
    const float* bm    = (const float*)d_in[8];
    const float* Wv    = (const float*)d_in[9];
    const float* bv    = (const float*)d_in[10];
    float* out = (float*)d_out;

    unsigned short* weff = (unsigned short*)d_ws;                    // 512*256*2 = 256 KiB
    float* beff = (float*)((char*)d_ws + (size_t)Nsz * Zsz * 2);     // + 2 KiB

    hidec_prep<<<Nsz, Zsz, 0, stream>>>(Wy, by, Wm, bm, Wv, bv, weff, beff);
    hidec_main<<<Bsz / BM, 256, 0, stream>>>(z, bx, miss, dmean, dvar, weff, beff, out);
}